// Round 1
// 280.528 us; speedup vs baseline: 1.1052x; 1.1052x over previous
//
#include <hip/hip_runtime.h>
#include <hip/hip_bf16.h>
#include <math.h>

constexpr int DXc = 1024;
constexpr int DZc = 1024;
constexpr int LXc = 4096;
constexpr int LZc = 4096;
constexpr int DAc = 1024;   // DATTN
constexpr int DOc = 1024;   // DOUT

typedef __attribute__((ext_vector_type(8))) short bf16x8;   // 8 bf16 = 4 VGPRs
typedef __attribute__((ext_vector_type(4))) float f32x4;

__device__ __forceinline__ ushort f2bf(float f) {
    __hip_bfloat16 h = __float2bfloat16(f);
    return *reinterpret_cast<ushort*>(&h);
}
__device__ __forceinline__ float bflo(unsigned u) {
    return __builtin_bit_cast(float, u << 16);
}
__device__ __forceinline__ float bfhi(unsigned u) {
    return __builtin_bit_cast(float, u & 0xffff0000u);
}

enum BiasMode { BIAS_NONE, BIAS_M, BIAS_N };

#define SCHED0() __builtin_amdgcn_sched_barrier(0)
// Raw barrier, pinned on both sides so the compiler cannot move ds_reads /
// global_load_lds across it (rule #18/#21 hazards). NO waitcnt drain here —
// that is the whole point of the counted-vmcnt pipeline (T4).
#define BAR2()   do { SCHED0(); __builtin_amdgcn_s_barrier(); SCHED0(); } while (0)
#define LGKM0()  do { asm volatile("s_waitcnt lgkmcnt(0)" ::: "memory"); SCHED0(); } while (0)
#define VMCNT(n) do { asm volatile("s_waitcnt vmcnt(" #n ")" ::: "memory"); SCHED0(); } while (0)

// ---------------------------------------------------------------------------
// 256x256 tile, BK=64, 8 waves (2M x 4N), 8-phase counted-vmcnt schedule
// (T2 swizzle + T3/T4 + T5).  C[m,n] = sum_k A[m,k]*B[n,k], A,B K-major bf16.
// K must be a multiple of 128 (2 K-tiles per iteration), K/64 >= 4.
//
// Interleaved wave->row mapping: A frag m (0..7) covers rows 32*m + wr*16 + lrow
// so quadrant (m-lo) touches ONLY A-half0, (m-hi) only A-half1; same for B with
// 64*n + wc*16.  Phase p reads exactly one half => half-granular staging slots:
//   p1: A1(U)   p2: A0(T+2)  p3: B0(T+2)  p4: B1(T+2)+vmcnt(6)
//   p5: A1(T+2) p6: A0(T+3)  p7: B0(T+3)  p8: B1(T+3)+vmcnt(6)
// Every slot is >=1 barrier after its region's last reader drained (verified),
// and vmcnt(6) (3 halves in flight) meets every read deadline (verified).
//
// LDS swizzle: physical = logical ^ (((logical>>7)&7)<<4) within each 128B row
// (rows are 64 bf16). Staging keeps the LDS dest linear (global_load_lds
// requirement) and inverse-permutes the per-lane GLOBAL source; reads apply
// the same XOR => ds_read_b128 spreads 16 same-column lanes over 8 16B slots.
// ---------------------------------------------------------------------------
template<BiasMode BMODE, bool OUT_BF16, bool SPLIT>
__device__ __forceinline__ void gemm256(
    const ushort* __restrict__ A, const ushort* __restrict__ B,
    const float* __restrict__ bias, void* __restrict__ Cv,
    int M, int N, int K, int lda, int ldb, int ldc,
    int m0, int n0, int kbase, int zsplit, char* smem)
{
    const int tid  = threadIdx.x;
    const int wid  = tid >> 6, lane = tid & 63;
    const int wr   = wid >> 2, wc = wid & 3;          // 2M x 4N waves
    const int lrow = lane & 15, quad = lane >> 4;
    const int swz  = (lrow & 7) << 4;
    const int cx0  = (quad * 16) ^ swz;               // byte col, kstep 0
    const int cx1  = (64 + quad * 16) ^ swz;          // byte col, kstep 1
    const int raB  = (wr * 16 + lrow) * 128;          // A per-lane row base (bytes)
    const int rbB  = (wc * 16 + lrow) * 128;          // B per-lane row base (bytes)

    char* const Ab0 = smem;                 // A buf0: 32 KB ([256][64] bf16)
    char* const Ab1 = smem + 32768;         // A buf1
    char* const Bb0 = smem + 65536;         // B buf0
    char* const Bb1 = smem + 98304;         // B buf1

    // Stage one half-tile (128 rows x 64 cols) = 2 x global_load_lds(16B).
    // LDS dest linear (wave-uniform base + lane*16); global source inverse-swizzled.
    auto stage = [&](const ushort* __restrict__ Mat, int ld, int r0, int kc,
                     char* dstBuf, int h) {
        #pragma unroll
        for (int r = 0; r < 2; ++r) {
            const int q = h * 16384 + r * 8192 + wid * 1024 + lane * 16; // phys LDS byte
            const int p = q ^ (((q >> 7) & 7) << 4);                    // logical byte
            const ushort* g = Mat + (size_t)(r0 + (p >> 7)) * ld + kc + ((p & 127) >> 1);
            __builtin_amdgcn_global_load_lds(
                (const __attribute__((address_space(1))) void*)g,
                (__attribute__((address_space(3))) void*)(dstBuf + h * 16384 + r * 8192 + wid * 1024),
                16, 0, 0);
        }
    };

    f32x4  acc[8][4] = {};
    bf16x8 alo[4][2], ahi[4][2], blo[2][2], bhi[2][2];

    auto ldLo = [&](char* Abuf, char* Bbuf) {       // 12 ds_read_b128
        #pragma unroll
        for (int m = 0; m < 4; ++m) {
            alo[m][0] = *reinterpret_cast<const bf16x8*>(Abuf + m * 4096 + raB + cx0);
            alo[m][1] = *reinterpret_cast<const bf16x8*>(Abuf + m * 4096 + raB + cx1);
        }
        #pragma unroll
        for (int n = 0; n < 2; ++n) {
            blo[n][0] = *reinterpret_cast<const bf16x8*>(Bbuf + n * 8192 + rbB + cx0);
            blo[n][1] = *reinterpret_cast<const bf16x8*>(Bbuf + n * 8192 + rbB + cx1);
        }
    };
    auto ldAhi = [&](char* Abuf) {                  // 8 ds_read_b128
        #pragma unroll
        for (int m = 0; m < 4; ++m) {
            ahi[m][0] = *reinterpret_cast<const bf16x8*>(Abuf + (m + 4) * 4096 + raB + cx0);
            ahi[m][1] = *reinterpret_cast<const bf16x8*>(Abuf + (m + 4) * 4096 + raB + cx1);
        }
    };
    auto ldBhi = [&](char* Bbuf) {                  // 4 ds_read_b128
        #pragma unroll
        for (int n = 0; n < 2; ++n) {
            bhi[n][0] = *reinterpret_cast<const bf16x8*>(Bbuf + (n + 2) * 8192 + rbB + cx0);
            bhi[n][1] = *reinterpret_cast<const bf16x8*>(Bbuf + (n + 2) * 8192 + rbB + cx1);
        }
    };
    auto mmaQ = [&](bf16x8 (&a)[4][2], bf16x8 (&b)[2][2], int mh, int nh) {  // 16 MFMA
        __builtin_amdgcn_s_setprio(1);
        #pragma unroll
        for (int m = 0; m < 4; ++m)
            #pragma unroll
            for (int n = 0; n < 2; ++n) {
                f32x4& c = acc[mh * 4 + m][nh * 2 + n];
                c = __builtin_amdgcn_mfma_f32_16x16x32_bf16(a[m][0], b[n][0], c, 0, 0, 0);
                c = __builtin_amdgcn_mfma_f32_16x16x32_bf16(a[m][1], b[n][1], c, 0, 0, 0);
            }
        __builtin_amdgcn_s_setprio(0);
    };

    const int NIT = K >> 7;   // iterations; 2 K-tiles (BK=64) each

    // Prologue: tile0 {A0,B0,B1,A1} then tile1 {A0,B0,B1}; A1(tile1) comes in-loop p1.
    stage(A, lda, m0, kbase,      Ab0, 0);
    stage(B, ldb, n0, kbase,      Bb0, 0);
    stage(B, ldb, n0, kbase,      Bb0, 1);
    stage(A, lda, m0, kbase,      Ab0, 1);
    VMCNT(4);
    stage(A, lda, m0, kbase + 64, Ab1, 0);
    stage(B, ldb, n0, kbase + 64, Bb1, 0);
    stage(B, ldb, n0, kbase + 64, Bb1, 1);
    VMCNT(6);                 // ensures all of tile0 resident
    BAR2();

    #pragma unroll 1
    for (int it = 0; it < NIT; ++it) {
        const bool st  = (it < NIT - 1);
        const int kU   = kbase + (2 * it + 1) * 64;
        const int kT2  = kbase + (2 * it + 2) * 64;
        const int kT3  = kbase + (2 * it + 3) * 64;

        // ---- p1: tile T (buf0), quadrant (m-lo, n-lo)
        ldLo(Ab0, Bb0);
        stage(A, lda, m0, kU, Ab1, 1);                    // A1(U) - always needed
        asm volatile("s_waitcnt lgkmcnt(8)" ::: "memory");
        BAR2(); LGKM0();
        mmaQ(alo, blo, 0, 0);
        BAR2();
        // ---- p2: (m-lo, n-hi)
        ldBhi(Bb0);
        if (st) stage(A, lda, m0, kT2, Ab0, 0);           // A0(T+2)
        BAR2(); LGKM0();
        mmaQ(alo, bhi, 0, 1);
        BAR2();
        // ---- p3: (m-hi, n-hi)
        ldAhi(Ab0);
        if (st) stage(B, ldb, n0, kT2, Bb0, 0);           // B0(T+2)
        BAR2(); LGKM0();
        mmaQ(ahi, bhi, 1, 1);
        BAR2();
        // ---- p4: (m-hi, n-lo); once-per-K-tile vmcnt
        if (st) { stage(B, ldb, n0, kT2, Bb0, 1); VMCNT(6); }   // B1(T+2)
        else    { VMCNT(0); }                             // epilogue drain
        BAR2();
        mmaQ(ahi, blo, 1, 0);
        BAR2();
        // ---- p5: tile U (buf1), quadrant (m-lo, n-lo)
        ldLo(Ab1, Bb1);
        if (st) stage(A, lda, m0, kT2, Ab0, 1);           // A1(T+2)
        asm volatile("s_waitcnt lgkmcnt(8)" ::: "memory");
        BAR2(); LGKM0();
        mmaQ(alo, blo, 0, 0);
        BAR2();
        // ---- p6: (m-lo, n-hi)
        ldBhi(Bb1);
        if (st) stage(A, lda, m0, kT3, Ab1, 0);           // A0(T+3)
        BAR2(); LGKM0();
        mmaQ(alo, bhi, 0, 1);
        BAR2();
        // ---- p7: (m-hi, n-hi)
        ldAhi(Ab1);
        if (st) stage(B, ldb, n0, kT3, Bb1, 0);           // B0(T+3)
        BAR2(); LGKM0();
        mmaQ(ahi, bhi, 1, 1);
        BAR2();
        // ---- p8: (m-hi, n-lo)
        if (st) { stage(B, ldb, n0, kT3, Bb1, 1); VMCNT(6); }   // B1(T+3)
        else    { VMCNT(0); }
        BAR2();
        mmaQ(ahi, blo, 1, 0);
        BAR2();
    }

    // Epilogue: row = m0 + 32m + wr*16 + quad*4 + r ; col = n0 + 64n + wc*16 + lrow
    float*  Cf = (float*)Cv + (SPLIT ? (size_t)zsplit * (size_t)M * ldc : 0);
    ushort* Cb = (ushort*)Cv;
    #pragma unroll
    for (int m = 0; m < 8; ++m) {
        const int rowb = m0 + 32 * m + wr * 16 + quad * 4;
        #pragma unroll
        for (int r = 0; r < 4; ++r) {
            const int row = rowb + r;
            const float bm = (BMODE == BIAS_M) ? bias[row] : 0.0f;
            #pragma unroll
            for (int n = 0; n < 4; ++n) {
                const int col = n0 + 64 * n + wc * 16 + lrow;
                float v = acc[m][n][r] + ((BMODE == BIAS_N) ? bias[col] : bm);
                if (OUT_BF16) Cb[(size_t)row * ldc + col] = f2bf(v);
                else          Cf[(size_t)row * ldc + col] = v;
            }
        }
    }
}

// ---------------------------------------------------------------------------
// Batched projection GEMM: one dispatch for q, k, v (192 blocks of 512 thr).
// ---------------------------------------------------------------------------
__global__ __launch_bounds__(512, 2)
void proj256_kernel(const ushort* __restrict__ XT, const ushort* __restrict__ ZT,
                    const ushort* __restrict__ Wqb, const ushort* __restrict__ Wkb,
                    const ushort* __restrict__ Wvb,
                    const float* __restrict__ bq, const float* __restrict__ bk,
                    const float* __restrict__ bv,
                    ushort* __restrict__ qT, ushort* __restrict__ kT,
                    ushort* __restrict__ vB)
{
    extern __shared__ char smem[];
    int b = blockIdx.x;
    if (b < 64) {
        gemm256<BIAS_N, true, false>(XT, Wqb, bq, qT, LXc, DAc, DXc, DXc, DXc, DAc,
                                     (b >> 2) * 256, (b & 3) * 256, 0, 0, smem);
    } else if (b < 128) {
        b -= 64;
        gemm256<BIAS_N, true, false>(ZT, Wkb, bk, kT, LZc, DAc, DZc, DZc, DZc, DAc,
                                     (b >> 2) * 256, (b & 3) * 256, 0, 0, smem);
    } else {
        b -= 128;
        gemm256<BIAS_M, true, false>(Wvb, ZT, bv, vB, DOc, LZc, DZc, DZc, DZc, LZc,
                                     (b >> 4) * 256, (b & 15) * 256, 0, 0, smem);
    }
}

// Score GEMM: sTb[x,z] = sum_d qT[x,d] kT[z,d]  (bf16 out, no mask). 256 blocks.
__global__ __launch_bounds__(512, 2)
void score256_kernel(const ushort* __restrict__ qT, const ushort* __restrict__ kT,
                     ushort* __restrict__ sTb)
{
    extern __shared__ char smem[];
    const int b = blockIdx.x;
    gemm256<BIAS_NONE, true, false>(qT, kT, nullptr, sTb, LXc, LZc, DAc, DAc, DAc, LZc,
                                    (b >> 4) * 256, (b & 15) * 256, 0, 0, smem);
}

// Out GEMM split-K=4: P[z][o][x] fp32 partials. grid (16,4,4) = 256 blocks.
__global__ __launch_bounds__(512, 2)
void out256_kernel(const ushort* __restrict__ vB, const ushort* __restrict__ sTb,
                   float* __restrict__ P)
{
    extern __shared__ char smem[];
    gemm256<BIAS_NONE, false, true>(vB, sTb, nullptr, P, DOc, LXc, LZc / 4,
                                    LZc, LZc, LXc,
                                    blockIdx.y * 256, blockIdx.x * 256,
                                    blockIdx.z * (LZc / 4), blockIdx.z, smem);
}

// ---------------------------------------------------------------------------
// Prep (one dispatch): X->XT bf16 transpose, Z->ZT, Wq/Wk/Wv fp32->bf16,
// mask (LZ,LX) int -> bitsT[x][z/32] packed transposed bitmask.
// ---------------------------------------------------------------------------
__global__ __launch_bounds__(256)
void prep_kernel(const float* __restrict__ X, const float* __restrict__ Z,
                 const float* __restrict__ Wq, const float* __restrict__ Wk,
                 const float* __restrict__ Wv, const int* __restrict__ mask,
                 ushort* __restrict__ XT, ushort* __restrict__ ZT,
                 ushort* __restrict__ Wqb, ushort* __restrict__ Wkb,
                 ushort* __restrict__ Wvb, unsigned* __restrict__ bits)
{
    __shared__ float tile[32][33];
    const int tid = threadIdx.x;
    int b = blockIdx.x;

    if (b < 8192) {   // two transposes, 4096 blocks each: (R=1024, C=4096)
        const float* in  = (b < 4096) ? X : Z;
        ushort*      out = (b < 4096) ? XT : ZT;
        const int local = b & 4095;
        const int bx = local & 127, by = local >> 7;
        const int c0 = bx * 32, r0 = by * 32;
        const int tx = tid & 31, ty = tid >> 5;          // 32 x 8
        #pragma unroll
        for (int i = 0; i < 32; i += 8)
            tile[ty + i][tx] = in[(size_t)(r0 + ty + i) * LXc + c0 + tx];
        __syncthreads();
        #pragma unroll
        for (int i = 0; i < 32; i += 8)
            out[(size_t)(c0 + ty + i) * DXc + r0 + tx] = f2bf(tile[tx][ty + i]);
        return;
    }
    if (b < 11264) {  // three weight converts, 1024 blocks each (1M elems)
        b -= 8192;
        const float* in  = (b < 1024) ? Wq : (b < 2048) ? Wk : Wv;
        ushort*      out = (b < 1024) ? Wqb : (b < 2048) ? Wkb : Wvb;
        const int local = b & 1023;
        const size_t i = ((size_t)local * 256 + tid) * 4;
        float4 f = *reinterpret_cast<const float4*>(in + i);
        ushort4 u;
        u.x = f2bf(f.x); u.y = f2bf(f.y); u.z = f2bf(f.z); u.w = f2bf(f.w);
        *reinterpret_cast<ushort4*>(out + i) = u;
        return;
    }
    // mask pack: 2048 blocks; block = (xb in [0,16), zb in [0,128))
    b -= 11264;
    const int xb = b & 15, zb = b >> 4;
    const int x  = xb * 256 + tid;
    const int z0 = zb * 32;
    unsigned w = 0;
    #pragma unroll 8
    for (int i = 0; i < 32; ++i)
        w |= (mask[(size_t)(z0 + i) * LXc + x] != 0 ? 1u : 0u) << i;
    bits[(size_t)x * (LZc / 32) + zb] = w;
}

// ---------------------------------------------------------------------------
// Row softmax over bf16 sTb (LX x LZ) with packed mask bits; scale 1/32,
// masked -> -1000/32; softmax over the row; bf16 in place.
// ---------------------------------------------------------------------------
__global__ __launch_bounds__(256)
void softmax_kernel(ushort* __restrict__ sTb, const unsigned* __restrict__ bits)
{
    const int x   = blockIdx.x;
    const int tid = threadIdx.x;
    ushort* row = sTb + (size_t)x * LZc;
    constexpr float scale = 1.0f / 32.0f;   // 1/sqrt(1024)
    constexpr float MASKV = -1000.0f / 32.0f;

    float v[16];
    float mx = -1e30f;
    #pragma unroll
    for (int r = 0; r < 2; ++r) {
        const uint4 pk = *reinterpret_cast<const uint4*>(row + (size_t)(r * 256 + tid) * 8);
        const unsigned* w = reinterpret_cast<const unsigned*>(&pk);
        const unsigned mb = (bits[(size_t)x * 128 + r * 64 + (tid >> 2)] >> ((tid & 3) * 8)) & 0xffu;
        #pragma unroll
        for (int j = 0; j < 4; ++j) {
            const float lo = ((mb >> (2 * j))     & 1u) ? bflo(w[j]) * scale : MASKV;
            const float hi = ((mb >> (2 * j + 1)) & 1u) ? bfhi(w[j]) * scale : MASKV;
            v[r * 8 + 2 * j]     = lo;
            v[r * 8 + 2 * j + 1] = hi;
            mx = fmaxf(mx, fmaxf(lo, hi));
        }
    }
    __shared__ float redmax[4];
    #pragma unroll
    for (int off = 32; off > 0; off >>= 1)
        mx = fmaxf(mx, __shfl_down(mx, off, 64));
    if ((tid & 63) == 0) redmax[tid >> 6] = mx;
    __syncthreads();
    mx = fmaxf(fmaxf(redmax[0], redmax[1]), fmaxf(redmax[2], redmax[3]));

    float sum = 0.0f;
    #pragma unroll
    for (int i = 0; i < 16; ++i) {
        v[i] = __expf(v[i] - mx);
        sum += v[i];
    }
    __shared__ float redsum[4];
    #pragma unroll
    for (int off = 32; off > 0; off >>= 1)
        sum += __shfl_down(sum, off, 64);
    if ((tid & 63) == 0) redsum[tid >> 6] = sum;
    __syncthreads();
    sum = redsum[0] + redsum[1] + redsum[2] + redsum[3];
    const float inv = 1.0f / sum;

    #pragma unroll
    for (int r = 0; r < 2; ++r) {
        uint4 pk;
        unsigned* w = reinterpret_cast<unsigned*>(&pk);
        #pragma unroll
        for (int j = 0; j < 4; ++j) {
            const unsigned lo = f2bf(v[r * 8 + 2 * j] * inv);
            const unsigned hi = f2bf(v[r * 8 + 2 * j + 1] * inv);
            w[j] = lo | (hi << 16);
        }
        *reinterpret_cast<uint4*>(row + (size_t)(r * 256 + tid) * 8) = pk;
    }
}

// Sum 4 fp32 partials -> fp32 out
__global__ __launch_bounds__(256)
void reduce_kernel(const float* __restrict__ P, float* __restrict__ out)
{
    constexpr size_t total = (size_t)DOc * LXc;
    const size_t i = ((size_t)blockIdx.x * 256 + threadIdx.x) * 4;
    float4 s = *reinterpret_cast<const float4*>(P + i);
    #pragma unroll
    for (int p = 1; p < 4; ++p) {
        const float4 t = *reinterpret_cast<const float4*>(P + (size_t)p * total + i);
        s.x += t.x; s.y += t.y; s.z += t.z; s.w += t.w;
    }
    *reinterpret_cast<float4*>(out + i) = s;
}

// ---------------------------------------------------------------------------
extern "C" void kernel_launch(void* const* d_in, const int* in_sizes, int n_in,
                              void* d_out, int out_size, void* d_ws, size_t ws_size,
                              hipStream_t stream)
{
    const float* X    = (const float*)d_in[0];
    const float* Z    = (const float*)d_in[1];
    const int*   mask = (const int*)  d_in[2];
    const float* Wq   = (const float*)d_in[3];
    const float* bq   = (const float*)d_in[4];
    const float* Wk   = (const float*)d_in[5];
    const float* bk   = (const float*)d_in[6];
    const float* Wv   = (const float*)d_in[7];
    const float* bv   = (const float*)d_in[8];
    float* out = (float*)d_out;

    // 128 KiB dynamic LDS opt-in (once; host-side, not a stream op).
    static bool inited = false;
    if (!inited) {
        (void)hipFuncSetAttribute((const void*)proj256_kernel,
                                  hipFuncAttributeMaxDynamicSharedMemorySize, 131072);
        (void)hipFuncSetAttribute((const void*)score256_kernel,
                                  hipFuncAttributeMaxDynamicSharedMemorySize, 131072);
        (void)hipFuncSetAttribute((const void*)out256_kernel,
                                  hipFuncAttributeMaxDynamicSharedMemorySize, 131072);
        inited = true;
    }

    // ws layout (106 MB). P (64 MB at offset 0) OVERLAYS XT/ZT/W/qT/kT --
    // all dead by the time the out GEMM writes P.
    char* ws = (char*)d_ws;
    ushort*   XT   = (ushort*)(ws);                   // 8 MB   [dead after proj]
    ushort*   ZT   = (ushort*)(ws + ( 8ull << 20));   // 8 MB   [dead after proj]
    ushort*   Wqb  = (ushort*)(ws + (16ull << 20));   // 2 MB   [dead after proj]
    ushort*   Wkb  = (ushort*)(ws + (18ull << 20));   // 2 MB   [dead after proj]
    ushort*   Wvb  = (ushort*)(ws + (20ull << 20));   // 2 MB   [dead after proj]
    ushort*   qT   = (ushort*)(ws + (22ull << 20));   // 8 MB   [dead after score]
    ushort*   kT   = (ushort*)(ws + (30ull << 20));   // 8 MB   [dead after score]
    float*    P    = (float*) (ws);                   // 64 MB  [out partials]
    ushort*   vB   = (ushort*)(ws + (64ull << 20));   // 8 MB
    ushort*   sTb  = (ushort*)(ws + (72ull << 20));   // 32 MB
    unsigned* bits = (unsigned*)(ws + (104ull << 20));// 2 MB

    prep_kernel<<<dim3(13312), 256, 0, stream>>>(X, Z, Wq, Wk, Wv, mask,
                                                 XT, ZT, Wqb, Wkb, Wvb, bits);
    proj256_kernel<<<dim3(192), 512, 131072, stream>>>(XT, ZT, Wqb, Wkb, Wvb,
                                                       bq, bk, bv, qT, kT, vB);
    score256_kernel<<<dim3(256), 512, 131072, stream>>>(qT, kT, sTb);
    softmax_kernel<<<dim3(LXc), 256, 0, stream>>>(sTb, bits);
    out256_kernel<<<dim3(16, 4, 4), 512, 131072, stream>>>(vB, sTb, P);
    reduce_kernel<<<dim3(DOc * LXc / 1024), 256, 0, stream>>>(P, out);
}